// Round 21
// baseline (258.878 us; speedup 1.0000x reference)
//
#include <hip/hip_runtime.h>
#include <stdint.h>

typedef unsigned short u16;
typedef unsigned int   u32;
typedef __attribute__((ext_vector_type(8))) __bf16 bf16x8;
typedef __attribute__((ext_vector_type(4))) float  f32x4;
typedef __attribute__((ext_vector_type(4))) short  s16x4;

#define NB  64
#define NQ  784
#define NK  196
#define NKP 208      // nk padded to 13*16
#define DM  512

static __device__ inline u16 f2bf(float f) {
  u32 u = __float_as_uint(f);
  u32 r = (u + 0x7fffu + ((u >> 16) & 1u)) >> 16;
  return (u16)r;
}

static __device__ inline bf16x8 ld8(const u16* p) {
  return *reinterpret_cast<const bf16x8*>(p);
}
static __device__ inline f32x4 mfma16(bf16x8 a, bf16x8 b, f32x4 c) {
  return __builtin_amdgcn_mfma_f32_16x16x32_bf16(a, b, c, 0, 0, 0);
}
// K=16 bf16 MFMA (4 bf16 per lane per operand)
static __device__ inline f32x4 mfma16k16(s16x4 a, s16x4 b, f32x4 c) {
#if __has_builtin(__builtin_amdgcn_mfma_f32_16x16x16bf16_1k)
  return __builtin_amdgcn_mfma_f32_16x16x16bf16_1k(a, b, c, 0, 0, 0);
#elif __has_builtin(__builtin_amdgcn_mfma_f32_16x16x16_bf16)
  typedef __attribute__((ext_vector_type(4))) __bf16 bf16x4_t;
  union { s16x4 s; bf16x4_t b; } ua, ub;
  ua.s = a; ub.s = b;
  return __builtin_amdgcn_mfma_f32_16x16x16_bf16(ua.b, ub.b, c, 0, 0, 0);
#else
  asm volatile("v_mfma_f32_16x16x16_bf16 %0, %1, %2, %0\n\ts_nop 7\n\ts_nop 7"
               : "+v"(c) : "v"(a), "v"(b));
  return c;
#endif
}

// wave-uniform float -> SGPR
static __device__ inline float sgpr_f(float x) {
  return __uint_as_float(__builtin_amdgcn_readfirstlane(__float_as_uint(x)));
}

// async global -> LDS, 16B per lane; LDS dest must be wave-uniform base
static __device__ inline void gl_lds16(const void* g, void* l) {
  __builtin_amdgcn_global_load_lds(
      (const __attribute__((address_space(1))) void*)g,
      (__attribute__((address_space(3))) void*)l, 16, 0, 0);
}

// ---------------- fused fp32 -> bf16 conversion of the 4 weight matrices ---------------
__global__ __launch_bounds__(256) void cvt4_kernel(const float* __restrict__ Wq,
                                                   const float* __restrict__ Wk,
                                                   const float* __restrict__ Wv,
                                                   const float* __restrict__ Wo,
                                                   u16* __restrict__ oq,
                                                   u16* __restrict__ ok,
                                                   u16* __restrict__ ov,
                                                   u16* __restrict__ oo) {
  int sel = blockIdx.x >> 8;
  int blk = blockIdx.x & 255;
  const float* in = (sel == 0) ? Wq : (sel == 1) ? Wk : (sel == 2) ? Wv : Wo;
  u16* out = (sel == 0) ? oq : (sel == 1) ? ok : (sel == 2) ? ov : oo;
  int i = (blk * 256 + threadIdx.x) * 4;
  float4 f = *reinterpret_cast<const float4*>(in + i);
  ushort4 o;
  o.x = f2bf(f.x); o.y = f2bf(f.y); o.z = f2bf(f.z); o.w = f2bf(f.w);
  *reinterpret_cast<ushort4*>(out + i) = o;
}

// ---------------- spatial-reduce + LayerNorm (reads ONLY the subsampled rows) ----------
// Round-21: queries fp32->bf16 copy eliminated (Q-proj consumes fp32 A
// directly); this kernel reads just 196/784 rows (26 MB vs 103 MB).
__global__ __launch_bounds__(256) void ln_kernel(const float* __restrict__ q,
                                                 const float* __restrict__ sr_w,
                                                 const float* __restrict__ sr_b,
                                                 const float* __restrict__ ln_w,
                                                 const float* __restrict__ ln_b,
                                                 u16* __restrict__ xln) {
  int w = blockIdx.x * 4 + (threadIdx.x >> 6);
  int lane = threadIdx.x & 63;
  if (w >= NB * NK) {
    int w2 = w - NB * NK;
    if (w2 < NB * 12) {
      int b = w2 / 12, pr = w2 % 12;
      u16* outp = xln + ((size_t)(b * NKP + NK + pr)) * DM;
      *reinterpret_cast<uint4*>(outp + lane * 8) = make_uint4(0u, 0u, 0u, 0u);
    }
    return;
  }
  int b = w / NK, np = w % NK;
  int src_n = (2 * (np / 14)) * 28 + 2 * (np % 14);
  const float* row = q + ((size_t)(b * NQ + src_n)) * DM;
  int c0 = lane * 4, c1 = 256 + lane * 4;
  float4 x0 = *reinterpret_cast<const float4*>(row + c0);
  float4 x1 = *reinterpret_cast<const float4*>(row + c1);
  float4 w0 = *reinterpret_cast<const float4*>(sr_w + c0);
  float4 w1 = *reinterpret_cast<const float4*>(sr_w + c1);
  float4 s0 = *reinterpret_cast<const float4*>(sr_b + c0);
  float4 s1 = *reinterpret_cast<const float4*>(sr_b + c1);
  float yv[8];
  yv[0] = x0.x * w0.x + s0.x; yv[1] = x0.y * w0.y + s0.y;
  yv[2] = x0.z * w0.z + s0.z; yv[3] = x0.w * w0.w + s0.w;
  yv[4] = x1.x * w1.x + s1.x; yv[5] = x1.y * w1.y + s1.y;
  yv[6] = x1.z * w1.z + s1.z; yv[7] = x1.w * w1.w + s1.w;
  float s = 0.f, ss = 0.f;
  #pragma unroll
  for (int i = 0; i < 8; i++) { s += yv[i]; ss += yv[i] * yv[i]; }
  #pragma unroll
  for (int off = 1; off < 64; off <<= 1) {
    s += __shfl_xor(s, off); ss += __shfl_xor(ss, off);
  }
  float mu = s * (1.f / 512.f);
  float var = ss * (1.f / 512.f) - mu * mu;
  float rs = rsqrtf(var + 1e-5f);
  float4 lw0 = *reinterpret_cast<const float4*>(ln_w + c0);
  float4 lw1 = *reinterpret_cast<const float4*>(ln_w + c1);
  float4 lb0 = *reinterpret_cast<const float4*>(ln_b + c0);
  float4 lb1 = *reinterpret_cast<const float4*>(ln_b + c1);
  ushort4 o0, o1;
  o0.x = f2bf((yv[0] - mu) * rs * lw0.x + lb0.x);
  o0.y = f2bf((yv[1] - mu) * rs * lw0.y + lb0.y);
  o0.z = f2bf((yv[2] - mu) * rs * lw0.z + lb0.z);
  o0.w = f2bf((yv[3] - mu) * rs * lw0.w + lb0.w);
  o1.x = f2bf((yv[4] - mu) * rs * lw1.x + lb1.x);
  o1.y = f2bf((yv[5] - mu) * rs * lw1.y + lb1.y);
  o1.z = f2bf((yv[6] - mu) * rs * lw1.z + lb1.z);
  o1.w = f2bf((yv[7] - mu) * rs * lw1.w + lb1.w);
  u16* outp = xln + ((size_t)(b * NKP + np)) * DM;
  *reinterpret_cast<ushort4*>(outp + c0) = o0;
  *reinterpret_cast<ushort4*>(outp + c1) = o1;
}

// ---------------- shared GEMM body (bf16 A): C = A[M,512]*W^T + bias -------------------
template <int OMODE>
static __device__ __forceinline__ void gemm_body(const u16* __restrict__ A,
                                                 const u16* __restrict__ Bw,
                                                 const float* __restrict__ bias,
                                                 void* __restrict__ Cptr,
                                                 int nt, int mt,
                                                 u16* Al0, u16* Al1,
                                                 u16* Bl0, u16* Bl1) {
  int wv = threadIdx.x >> 6, lane = threadIdx.x & 63;
  int lr = lane & 15, lg = lane >> 4;
  int wr = wv >> 1, wc = wv & 1;
  int row0 = mt * 128, col0 = nt * 128;

  auto stage = [&](int kk, int bi) {
    u16* Al = bi ? Al1 : Al0;
    u16* Bl = bi ? Bl1 : Bl0;
    #pragma unroll
    for (int i = 0; i < 4; i++) {
      int t = wv * 4 + i;                    // 0..15
      int rr = (t & 7) * 16 + (lane >> 2);
      int cc = lane & 3;
      if (t < 8) {
        gl_lds16(A + (size_t)(row0 + rr) * DM + kk + cc * 8, (char*)Al + t * 1024);
      } else {
        gl_lds16(Bw + (size_t)(col0 + rr) * DM + kk + cc * 8, (char*)Bl + (t - 8) * 1024);
      }
    }
  };

  f32x4 acc[4][4] = {};
  stage(0, 0);
  __syncthreads();
  for (int s = 0; s < 16; s++) {
    int bi = s & 1;
    if (s < 15) stage((s + 1) * 32, bi ^ 1);
    u16* Al = bi ? Al1 : Al0;
    u16* Bl = bi ? Bl1 : Bl0;
    bf16x8 am[4], bn[4];
    #pragma unroll
    for (int m = 0; m < 4; m++)
      am[m] = ld8(Al + (wr * 64 + m * 16 + lr) * 32 + lg * 8);
    #pragma unroll
    for (int n = 0; n < 4; n++)
      bn[n] = ld8(Bl + (wc * 64 + n * 16 + lr) * 32 + lg * 8);
    #pragma unroll
    for (int m = 0; m < 4; m++)
      #pragma unroll
      for (int n = 0; n < 4; n++)
        acc[m][n] = mfma16(am[m], bn[n], acc[m][n]);
    __syncthreads();
  }
  if (OMODE == 2) {
    #pragma unroll
    for (int n = 0; n < 4; n++) {
      int col = col0 + wc * 64 + n * 16 + lr;
      float bs = bias[col];
      #pragma unroll
      for (int m = 0; m < 4; m++) {
        int rbase = row0 + wr * 64 + m * 16 + lg * 4;
        int bb = rbase / NKP;
        int kr = rbase % NKP;          // kr&15 == lg*4
        ushort4 o4;
        o4.x = f2bf(acc[m][n][0] + bs);
        o4.y = f2bf(acc[m][n][1] + bs);
        o4.z = f2bf(acc[m][n][2] + bs);
        o4.w = f2bf(acc[m][n][3] + bs);
        size_t dst = (((size_t)bb * 13 + (kr >> 4)) * 512 + col) * 16 + (kr & 15);
        *reinterpret_cast<ushort4*>(&((u16*)Cptr)[dst]) = o4;
      }
    }
  } else {
    #pragma unroll
    for (int n = 0; n < 4; n++) {
      int col = col0 + wc * 64 + n * 16 + lr;
      float bs = bias[col];
      #pragma unroll
      for (int m = 0; m < 4; m++) {
        #pragma unroll
        for (int r = 0; r < 4; r++) {
          int row = row0 + wr * 64 + m * 16 + lg * 4 + r;
          float v = acc[m][n][r] + bs;
          if (OMODE == 0) {
            ((u16*)Cptr)[(size_t)row * DM + col] = f2bf(v);
          } else {
            ((float*)Cptr)[(size_t)row * DM + col] = v;
          }
        }
      }
    }
  }
}

// XCD-local decode: id = 32a + 8b + c  ->  nt = b, mt = c + 8a.
static __device__ inline void xcd_decode(int id, int& nt, int& mt) {
  nt = (id >> 3) & 3;
  mt = (id & 7) + 8 * (id >> 5);
}

// ---------------- Q-proj with fp32 A (T14 reg-staged cvt), bf16 out --------------------
// A-tile staged via registers: issue 4x float4 loads for step s+1 EARLY,
// compute step s (MFMA), then cvt+ds_write into the back buffer (the vmcnt
// wait lands after the MFMAs -> HBM latency hidden). B staged via gl_lds16.
__global__ __launch_bounds__(256) void qgemm_kernel(const float* __restrict__ A,
                                                    const u16* __restrict__ Bw,
                                                    const float* __restrict__ bias,
                                                    u16* __restrict__ Cptr) {
  __shared__ __align__(16) u16 Al[2][128 * 32];
  __shared__ __align__(16) u16 Bl[2][128 * 32];
  int nt, mt;
  xcd_decode(blockIdx.x, nt, mt);
  int wv = threadIdx.x >> 6, lane = threadIdx.x & 63;
  int lr = lane & 15, lg = lane >> 4;
  int wr = wv >> 1, wc = wv & 1;
  int row0 = mt * 128, col0 = nt * 128;
  int arow = threadIdx.x >> 1, ahalf = threadIdx.x & 1;
  const float* asrc = A + (size_t)(row0 + arow) * DM + ahalf * 16;

  float4 ar[4];
  auto loadA = [&](int kk) {
    #pragma unroll
    for (int i = 0; i < 4; i++)
      ar[i] = *reinterpret_cast<const float4*>(asrc + kk + i * 4);
  };
  auto writeA = [&](u16* Alw) {
    union { u16 s[16]; uint4 u[2]; } pk;
    const float* f = reinterpret_cast<const float*>(ar);
    #pragma unroll
    for (int i = 0; i < 16; i++) pk.s[i] = f2bf(f[i]);
    *reinterpret_cast<uint4*>(Alw + arow * 32 + ahalf * 16) = pk.u[0];
    *reinterpret_cast<uint4*>(Alw + arow * 32 + ahalf * 16 + 8) = pk.u[1];
  };
  auto stageB = [&](int kk, u16* Blw) {
    #pragma unroll
    for (int i = 0; i < 2; i++) {
      int t = wv * 2 + i;   // 0..7
      gl_lds16(Bw + (size_t)(col0 + t * 16 + (lane >> 2)) * DM + kk + (lane & 3) * 8,
               (char*)Blw + t * 1024);
    }
  };

  f32x4 acc[4][4] = {};
  loadA(0); writeA(&Al[0][0]); stageB(0, &Bl[0][0]);
  __syncthreads();
  for (int s = 0; s < 16; s++) {
    int bi = s & 1;
    u16* Alc = &Al[bi][0];
    u16* Blc = &Bl[bi][0];
    u16* Aln = &Al[bi ^ 1][0];
    u16* Bln = &Bl[bi ^ 1][0];
    if (s < 15) { loadA((s + 1) * 32); stageB((s + 1) * 32, Bln); }
    bf16x8 am[4], bn[4];
    #pragma unroll
    for (int m = 0; m < 4; m++)
      am[m] = ld8(Alc + (wr * 64 + m * 16 + lr) * 32 + lg * 8);
    #pragma unroll
    for (int n = 0; n < 4; n++)
      bn[n] = ld8(Blc + (wc * 64 + n * 16 + lr) * 32 + lg * 8);
    #pragma unroll
    for (int m = 0; m < 4; m++)
      #pragma unroll
      for (int n = 0; n < 4; n++)
        acc[m][n] = mfma16(am[m], bn[n], acc[m][n]);
    if (s < 15) writeA(Aln);   // vmcnt wait for loadA lands here, after MFMAs
    __syncthreads();
  }
  #pragma unroll
  for (int n = 0; n < 4; n++) {
    int col = col0 + wc * 64 + n * 16 + lr;
    float bs = bias[col];
    #pragma unroll
    for (int m = 0; m < 4; m++) {
      #pragma unroll
      for (int r = 0; r < 4; r++) {
        int row = row0 + wr * 64 + m * 16 + lg * 4 + r;
        Cptr[(size_t)row * DM + col] = f2bf(acc[m][n][r] + bs);
      }
    }
  }
}

// fused K-proj [0,416) + V-proj [416,832), bf16 A, XCD-local
__global__ __launch_bounds__(256) void kvgemm_kernel(const u16* __restrict__ xln,
                                                     const u16* __restrict__ Wk,
                                                     const float* __restrict__ bk,
                                                     void* __restrict__ Kout,
                                                     const u16* __restrict__ Wv,
                                                     const float* __restrict__ bv,
                                                     void* __restrict__ Vout) {
  __shared__ __align__(16) u16 Al[2][128 * 32];
  __shared__ __align__(16) u16 Bl[2][128 * 32];
  int id = blockIdx.x;
  int nt, mt;
  if (id < 416) {
    xcd_decode(id, nt, mt);
    gemm_body<0>(xln, Wk, bk, Kout, nt, mt,
                 &Al[0][0], &Al[1][0], &Bl[0][0], &Bl[1][0]);
  } else {
    xcd_decode(id - 416, nt, mt);
    gemm_body<2>(xln, Wv, bv, Vout, nt, mt,
                 &Al[0][0], &Al[1][0], &Bl[0][0], &Bl[1][0]);
  }
}

// O-proj (fp32 out), XCD-local 1-D grid
__global__ __launch_bounds__(256) void ogemm_kernel(const u16* __restrict__ A,
                                                    const u16* __restrict__ Bw,
                                                    const float* __restrict__ bias,
                                                    void* __restrict__ Cptr) {
  __shared__ __align__(16) u16 Al[2][128 * 32];
  __shared__ __align__(16) u16 Bl[2][128 * 32];
  int nt, mt;
  xcd_decode(blockIdx.x, nt, mt);
  gemm_body<1>(A, Bw, bias, Cptr, nt, mt,
               &Al[0][0], &Al[1][0], &Bl[0][0], &Bl[1][0]);
}

// ---------------- fused attn: 512 threads, 8 waves, ONE head per wave ------------------
// (unchanged from round 19/20: VGPR=64, occupancy 35%, 98us)
__global__ __launch_bounds__(512) void attn_kernel(const u16* __restrict__ Q,
                                                   const u16* __restrict__ K,
                                                   const u16* __restrict__ VTt,
                                                   const float* __restrict__ tw,
                                                   u16* __restrict__ Oat) {
  __shared__ __align__(16) u16 Kl[16 * 512];      // 16KB, chunk-major, single buf
  __shared__ __align__(16) float s2[2][16 * 256]; // 2 x 16KB, lane-order tiles
  int i = blockIdx.x;
  int g8 = i & 7;            // XCD group == b%8
  int j = i >> 3;            // 0..199
  int qc = j % 25;
  int b = g8 + 8 * (j / 25);
  int tid = threadIdx.x, wv = tid >> 6, lane = tid & 63;
  int lr = lane & 15, lg = lane >> 4;
  int q0A = qc * 32;
  int q0B = (qc < 24) ? (q0A + 16) : q0A;   // tail duplicates tile A

  const u16* Kb = K + (size_t)b * NKP * DM;
  const u16* Vtb = VTt + (size_t)b * 13 * 8192;

  float w0[8];
  #pragma unroll
  for (int h = 0; h < 8; h++)
    w0[h] = sgpr_f(tw[wv * 8 + h] * 0.125f);

  bf16x8 qr[2][2];   // [tile][half]
  #pragma unroll
  for (int t = 0; t < 2; t++) {
    const u16* Qb = Q + ((size_t)b * NQ + (t ? q0B : q0A)) * DM;
    qr[t][0] = ld8(Qb + (size_t)lr * DM + wv * 64 + lg * 8);
    qr[t][1] = ld8(Qb + (size_t)lr * DM + wv * 64 + 32 + lg * 8);
  }

  auto stageK = [&](int kt) {
    #pragma unroll
    for (int i2 = 0; i2 < 2; i2++) {
      int g = wv * 2 + i2;
      gl_lds16(Kb + (size_t)(kt * 16 + (lane & 15)) * DM + (g * 4 + (lane >> 4)) * 8,
               (char*)Kl + g * 1024);
    }
  };
  stageK(0);
  __syncthreads();

  f32x4 o[2][4] = {};      // [tile][j]
  float sumA = 0.f, sumB = 0.f;
  s16x4 vb[4];

  auto mixpv = [&](int ktm, int sbi) {
    bool masked = (ktm == 12) && (lg != 0);   // k >= 196
    s16x4 pa[2];
    #pragma unroll
    for (int t = 0; t < 2; t++) {
      f32x4 sa = {0.f, 0.f, 0.f, 0.f};
      #pragma unroll
      for (int h = 0; h < 8; h++) {
        f32x4 scv = *reinterpret_cast<const f32x4*>(
            &s2[sbi][0] + (t * 8 + h) * 256 + lane * 4);
        sa += scv * w0[h];
      }
      float e0 = masked ? 0.f : __expf(sa[0]);
      float e1 = masked ? 0.f : __expf(sa[1]);
      float e2 = masked ? 0.f : __expf(sa[2]);
      float e3 = masked ? 0.f : __expf(sa[3]);
      if (t == 0) sumA += (e0 + e1) + (e2 + e3);
      else        sumB += (e0 + e1) + (e2 + e3);
      union { __bf16 e[4]; s16x4 sv; } pk;
      pk.e[0] = (__bf16)e0; pk.e[1] = (__bf16)e1;
      pk.e[2] = (__bf16)e2; pk.e[3] = (__bf16)e3;
      pa[t] = pk.sv;
    }
    __builtin_amdgcn_s_setprio(1);
    #pragma unroll
    for (int t = 0; t < 2; t++) {
      #pragma unroll
      for (int j2 = 0; j2 < 4; j2++)
        o[t][j2] = mfma16k16(pa[t], vb[j2], o[t][j2]);
    }
    __builtin_amdgcn_s_setprio(0);
  };

  for (int kt = 0; kt < 13; kt++) {
    int bi = kt & 1;

    if (kt > 0) {
      #pragma unroll
      for (int j2 = 0; j2 < 4; j2++) {
        int d = wv * 64 + j2 * 16 + lr;
        vb[j2] = *reinterpret_cast<const s16x4*>(
            Vtb + (size_t)(kt - 1) * 8192 + d * 16 + lg * 4);
      }
    }

    const u16* kbase = Kl + lg * 128 + lr * 8;
    __builtin_amdgcn_s_setprio(1);
    {
      bf16x8 kf0 = ld8(kbase + wv * 1024);
      bf16x8 kf1 = ld8(kbase + wv * 1024 + 512);
      #pragma unroll
      for (int t = 0; t < 2; t++) {
        f32x4 tt = {0.f, 0.f, 0.f, 0.f};
        tt = mfma16(kf0, qr[t][0], tt);
        tt = mfma16(kf1, qr[t][1], tt);
        *reinterpret_cast<f32x4*>(&s2[bi][0] + (t * 8 + wv) * 256 + lane * 4) = tt;
      }
    }
    __builtin_amdgcn_s_setprio(0);

    asm volatile("s_waitcnt lgkmcnt(0)" ::: "memory");
    __builtin_amdgcn_sched_barrier(0);
    if (kt < 12) stageK(kt + 1);

    if (kt > 0) mixpv(kt - 1, bi ^ 1);

    __syncthreads();
  }
  {
    #pragma unroll
    for (int j2 = 0; j2 < 4; j2++) {
      int d = wv * 64 + j2 * 16 + lr;
      vb[j2] = *reinterpret_cast<const s16x4*>(
          Vtb + (size_t)12 * 8192 + d * 16 + lg * 4);
    }
    mixpv(12, 0);
  }

  sumA += __shfl_xor(sumA, 16); sumA += __shfl_xor(sumA, 32);
  sumB += __shfl_xor(sumB, 16); sumB += __shfl_xor(sumB, 32);
  float ivA = 1.0f / sumA, ivB = 1.0f / sumB;
  #pragma unroll
  for (int t = 0; t < 2; t++) {
    if (t == 1 && qc == 24) break;   // tail: tile B is a duplicate
    int q0 = t ? q0B : q0A;
    float ivsrc = t ? ivB : ivA;
    #pragma unroll
    for (int r = 0; r < 4; r++) {
      int q = lg * 4 + r;
      float iv = __shfl(ivsrc, q);   // sum lives at lane lr == q
      #pragma unroll
      for (int j2 = 0; j2 < 4; j2++) {
        Oat[((size_t)(b * NQ + q0 + q)) * DM + wv * 64 + j2 * 16 + lr] =
            f2bf(o[t][j2][r] * iv);
      }
    }
  }
}

// ---------------- launch ----------------
extern "C" void kernel_launch(void* const* d_in, const int* in_sizes, int n_in,
                              void* d_out, int out_size, void* d_ws, size_t ws_size,
                              hipStream_t stream) {
  const float* queries = (const float*)d_in[0];
  const float* Wq = (const float*)d_in[3];
  const float* bq = (const float*)d_in[4];
  const float* Wk = (const float*)d_in[5];
  const float* bk = (const float*)d_in[6];
  const float* Wv = (const float*)d_in[7];
  const float* bv = (const float*)d_in[8];
  const float* Wo = (const float*)d_in[9];
  const float* bo = (const float*)d_in[10];
  const float* sr_w = (const float*)d_in[11];
  const float* sr_b = (const float*)d_in[12];
  const float* ln_w = (const float*)d_in[13];
  const float* ln_b = (const float*)d_in[14];
  const float* tw = (const float*)d_in[15];

  char* ws = (char*)d_ws;
  u16* wq_bf = (u16*)(ws + 0);          // 512KB
  u16* wk_bf = (u16*)(ws + 524288);
  u16* wv_bf = (u16*)(ws + 1048576);
  u16* wo_bf = (u16*)(ws + 1572864);
  u16* xln   = (u16*)(ws + 2097152);    // 64*208*512*2 = 13,631,488
  u16* Kbuf  = (u16*)(ws + 15728640);   // 13,631,488
  u16* VTt   = (u16*)(ws + 29360128);   // 64*13*512*16*2 = 13,631,488
  u16* Qbuf  = (u16*)(ws + 42991616);   // 64*784*512*2 = 51,380,224
  u16* Oat   = (u16*)(ws + 94371840);   // 51,380,224 -> end 145,752,064
  if (ws_size < 145752064u) return;     // fail loudly (output stays poisoned)

  // all 4 weight conversions in ONE launch (1024 blocks)
  cvt4_kernel<<<1024, 256, 0, stream>>>(Wq, Wk, Wv, Wo,
                                        wq_bf, wk_bf, wv_bf, wo_bf);

  // spatial-reduce + LN (reads only subsampled rows): 64*196 + 64*12 waves
  ln_kernel<<<(NB * NK + NB * 12 + 3) / 4, 256, 0, stream>>>(
      queries, sr_w, sr_b, ln_w, ln_b, xln);

  // Q = queries(fp32) @ Wq^T + bq, reg-staged cvt, XCD-local
  qgemm_kernel<<<1568, 256, 0, stream>>>(queries, wq_bf, bq, Qbuf);
  // K-proj + V-proj (bf16 A = xln), XCD-local
  kvgemm_kernel<<<832, 256, 0, stream>>>(xln, wk_bf, bk, Kbuf,
                                         wv_bf, bv, VTt);

  attn_kernel<<<dim3(1600), 512, 0, stream>>>(Qbuf, Kbuf, VTt, tw, Oat);

  // out = Oat @ Wo^T + bo  (fp32 out), XCD-local
  ogemm_kernel<<<1568, 256, 0, stream>>>(Oat, wo_bf, bo, d_out);
}

// Round 22
// 240.865 us; speedup vs baseline: 1.0748x; 1.0748x over previous
//
#include <hip/hip_runtime.h>
#include <stdint.h>

typedef unsigned short u16;
typedef unsigned int   u32;
typedef __attribute__((ext_vector_type(8))) __bf16 bf16x8;
typedef __attribute__((ext_vector_type(4))) float  f32x4;
typedef __attribute__((ext_vector_type(4))) short  s16x4;

#define NB  64
#define NQ  784
#define NK  196
#define NKP 208      // nk padded to 13*16
#define DM  512

static __device__ inline u16 f2bf(float f) {
  u32 u = __float_as_uint(f);
  u32 r = (u + 0x7fffu + ((u >> 16) & 1u)) >> 16;
  return (u16)r;
}

static __device__ inline bf16x8 ld8(const u16* p) {
  return *reinterpret_cast<const bf16x8*>(p);
}
static __device__ inline f32x4 mfma16(bf16x8 a, bf16x8 b, f32x4 c) {
  return __builtin_amdgcn_mfma_f32_16x16x32_bf16(a, b, c, 0, 0, 0);
}
// K=16 bf16 MFMA (4 bf16 per lane per operand)
static __device__ inline f32x4 mfma16k16(s16x4 a, s16x4 b, f32x4 c) {
#if __has_builtin(__builtin_amdgcn_mfma_f32_16x16x16bf16_1k)
  return __builtin_amdgcn_mfma_f32_16x16x16bf16_1k(a, b, c, 0, 0, 0);
#elif __has_builtin(__builtin_amdgcn_mfma_f32_16x16x16_bf16)
  typedef __attribute__((ext_vector_type(4))) __bf16 bf16x4_t;
  union { s16x4 s; bf16x4_t b; } ua, ub;
  ua.s = a; ub.s = b;
  return __builtin_amdgcn_mfma_f32_16x16x16_bf16(ua.b, ub.b, c, 0, 0, 0);
#else
  asm volatile("v_mfma_f32_16x16x16_bf16 %0, %1, %2, %0\n\ts_nop 7\n\ts_nop 7"
               : "+v"(c) : "v"(a), "v"(b));
  return c;
#endif
}

// wave-uniform float -> SGPR
static __device__ inline float sgpr_f(float x) {
  return __uint_as_float(__builtin_amdgcn_readfirstlane(__float_as_uint(x)));
}

// async global -> LDS, 16B per lane; LDS dest must be wave-uniform base
static __device__ inline void gl_lds16(const void* g, void* l) {
  __builtin_amdgcn_global_load_lds(
      (const __attribute__((address_space(1))) void*)g,
      (__attribute__((address_space(3))) void*)l, 16, 0, 0);
}

// bf16x4 (as uint2) -> f32x4: shift/mask only (1 VALU per float)
static __device__ inline f32x4 unpk4(uint2 v) {
  f32x4 r;
  r[0] = __uint_as_float(v.x << 16);
  r[1] = __uint_as_float(v.x & 0xffff0000u);
  r[2] = __uint_as_float(v.y << 16);
  r[3] = __uint_as_float(v.y & 0xffff0000u);
  return r;
}

// ---------------- fused fp32 -> bf16 conversion of the 4 weight matrices ---------------
__global__ __launch_bounds__(256) void cvt4_kernel(const float* __restrict__ Wq,
                                                   const float* __restrict__ Wk,
                                                   const float* __restrict__ Wv,
                                                   const float* __restrict__ Wo,
                                                   u16* __restrict__ oq,
                                                   u16* __restrict__ ok,
                                                   u16* __restrict__ ov,
                                                   u16* __restrict__ oo) {
  int sel = blockIdx.x >> 8;
  int blk = blockIdx.x & 255;
  const float* in = (sel == 0) ? Wq : (sel == 1) ? Wk : (sel == 2) ? Wv : Wo;
  u16* out = (sel == 0) ? oq : (sel == 1) ? ok : (sel == 2) ? ov : oo;
  int i = (blk * 256 + threadIdx.x) * 4;
  float4 f = *reinterpret_cast<const float4*>(in + i);
  ushort4 o;
  o.x = f2bf(f.x); o.y = f2bf(f.y); o.z = f2bf(f.z); o.w = f2bf(f.w);
  *reinterpret_cast<ushort4*>(out + i) = o;
}

// ---------------- fused queries cvt (fp32->bf16) + spatial-reduce LayerNorm ------------
__global__ __launch_bounds__(256) void cvtln_kernel(const float* __restrict__ q,
                                                    const float* __restrict__ sr_w,
                                                    const float* __restrict__ sr_b,
                                                    const float* __restrict__ ln_w,
                                                    const float* __restrict__ ln_b,
                                                    u16* __restrict__ qbf,
                                                    u16* __restrict__ xln) {
  int w = blockIdx.x * 4 + (threadIdx.x >> 6);
  int lane = threadIdx.x & 63;
  if (w >= NB * NQ) {
    int w2 = w - NB * NQ;
    if (w2 < NB * 12) {
      int b = w2 / 12, pr = w2 % 12;
      u16* outp = xln + ((size_t)(b * NKP + NK + pr)) * DM;
      *reinterpret_cast<uint4*>(outp + lane * 8) = make_uint4(0u, 0u, 0u, 0u);
    }
    return;
  }
  int b = w / NQ, n = w % NQ;
  const float* row = q + ((size_t)w) * DM;
  int c0 = lane * 4, c1 = 256 + lane * 4;
  float4 x0 = *reinterpret_cast<const float4*>(row + c0);
  float4 x1 = *reinterpret_cast<const float4*>(row + c1);
  u16* qp = qbf + (size_t)w * DM;
  ushort4 q0, q1;
  q0.x = f2bf(x0.x); q0.y = f2bf(x0.y); q0.z = f2bf(x0.z); q0.w = f2bf(x0.w);
  q1.x = f2bf(x1.x); q1.y = f2bf(x1.y); q1.z = f2bf(x1.z); q1.w = f2bf(x1.w);
  *reinterpret_cast<ushort4*>(qp + c0) = q0;
  *reinterpret_cast<ushort4*>(qp + c1) = q1;
  int y = n / 28, x = n % 28;
  if ((y & 1) | (x & 1)) return;
  int np = (y >> 1) * 14 + (x >> 1);
  float4 w0 = *reinterpret_cast<const float4*>(sr_w + c0);
  float4 w1 = *reinterpret_cast<const float4*>(sr_w + c1);
  float4 s0 = *reinterpret_cast<const float4*>(sr_b + c0);
  float4 s1 = *reinterpret_cast<const float4*>(sr_b + c1);
  float yv[8];
  yv[0] = x0.x * w0.x + s0.x; yv[1] = x0.y * w0.y + s0.y;
  yv[2] = x0.z * w0.z + s0.z; yv[3] = x0.w * w0.w + s0.w;
  yv[4] = x1.x * w1.x + s1.x; yv[5] = x1.y * w1.y + s1.y;
  yv[6] = x1.z * w1.z + s1.z; yv[7] = x1.w * w1.w + s1.w;
  float s = 0.f, ss = 0.f;
  #pragma unroll
  for (int i = 0; i < 8; i++) { s += yv[i]; ss += yv[i] * yv[i]; }
  #pragma unroll
  for (int off = 1; off < 64; off <<= 1) {
    s += __shfl_xor(s, off); ss += __shfl_xor(ss, off);
  }
  float mu = s * (1.f / 512.f);
  float var = ss * (1.f / 512.f) - mu * mu;
  float rs = rsqrtf(var + 1e-5f);
  float4 lw0 = *reinterpret_cast<const float4*>(ln_w + c0);
  float4 lw1 = *reinterpret_cast<const float4*>(ln_w + c1);
  float4 lb0 = *reinterpret_cast<const float4*>(ln_b + c0);
  float4 lb1 = *reinterpret_cast<const float4*>(ln_b + c1);
  ushort4 o0, o1;
  o0.x = f2bf((yv[0] - mu) * rs * lw0.x + lb0.x);
  o0.y = f2bf((yv[1] - mu) * rs * lw0.y + lb0.y);
  o0.z = f2bf((yv[2] - mu) * rs * lw0.z + lb0.z);
  o0.w = f2bf((yv[3] - mu) * rs * lw0.w + lb0.w);
  o1.x = f2bf((yv[4] - mu) * rs * lw1.x + lb1.x);
  o1.y = f2bf((yv[5] - mu) * rs * lw1.y + lb1.y);
  o1.z = f2bf((yv[6] - mu) * rs * lw1.z + lb1.z);
  o1.w = f2bf((yv[7] - mu) * rs * lw1.w + lb1.w);
  u16* outp = xln + ((size_t)(b * NKP + np)) * DM;
  *reinterpret_cast<ushort4*>(outp + c0) = o0;
  *reinterpret_cast<ushort4*>(outp + c1) = o1;
}

// ---------------- shared GEMM body: C[M,512] = A[M,512]*W[512,512]^T + bias ------------
template <int OMODE>
static __device__ __forceinline__ void gemm_body(const u16* __restrict__ A,
                                                 const u16* __restrict__ Bw,
                                                 const float* __restrict__ bias,
                                                 void* __restrict__ Cptr,
                                                 int nt, int mt,
                                                 u16* Al0, u16* Al1,
                                                 u16* Bl0, u16* Bl1) {
  int wv = threadIdx.x >> 6, lane = threadIdx.x & 63;
  int lr = lane & 15, lg = lane >> 4;
  int wr = wv >> 1, wc = wv & 1;
  int row0 = mt * 128, col0 = nt * 128;

  auto stage = [&](int kk, int bi) {
    u16* Al = bi ? Al1 : Al0;
    u16* Bl = bi ? Bl1 : Bl0;
    #pragma unroll
    for (int i = 0; i < 4; i++) {
      int t = wv * 4 + i;                    // 0..15
      int rr = (t & 7) * 16 + (lane >> 2);
      int cc = lane & 3;
      if (t < 8) {
        gl_lds16(A + (size_t)(row0 + rr) * DM + kk + cc * 8, (char*)Al + t * 1024);
      } else {
        gl_lds16(Bw + (size_t)(col0 + rr) * DM + kk + cc * 8, (char*)Bl + (t - 8) * 1024);
      }
    }
  };

  f32x4 acc[4][4] = {};
  stage(0, 0);
  __syncthreads();
  for (int s = 0; s < 16; s++) {
    int bi = s & 1;
    if (s < 15) stage((s + 1) * 32, bi ^ 1);
    u16* Al = bi ? Al1 : Al0;
    u16* Bl = bi ? Bl1 : Bl0;
    bf16x8 am[4], bn[4];
    #pragma unroll
    for (int m = 0; m < 4; m++)
      am[m] = ld8(Al + (wr * 64 + m * 16 + lr) * 32 + lg * 8);
    #pragma unroll
    for (int n = 0; n < 4; n++)
      bn[n] = ld8(Bl + (wc * 64 + n * 16 + lr) * 32 + lg * 8);
    #pragma unroll
    for (int m = 0; m < 4; m++)
      #pragma unroll
      for (int n = 0; n < 4; n++)
        acc[m][n] = mfma16(am[m], bn[n], acc[m][n]);
    __syncthreads();
  }
  if (OMODE == 2) {
    #pragma unroll
    for (int n = 0; n < 4; n++) {
      int col = col0 + wc * 64 + n * 16 + lr;
      float bs = bias[col];
      #pragma unroll
      for (int m = 0; m < 4; m++) {
        int rbase = row0 + wr * 64 + m * 16 + lg * 4;
        int bb = rbase / NKP;
        int kr = rbase % NKP;          // kr&15 == lg*4
        ushort4 o4;
        o4.x = f2bf(acc[m][n][0] + bs);
        o4.y = f2bf(acc[m][n][1] + bs);
        o4.z = f2bf(acc[m][n][2] + bs);
        o4.w = f2bf(acc[m][n][3] + bs);
        size_t dst = (((size_t)bb * 13 + (kr >> 4)) * 512 + col) * 16 + (kr & 15);
        *reinterpret_cast<ushort4*>(&((u16*)Cptr)[dst]) = o4;
      }
    }
  } else {
    #pragma unroll
    for (int n = 0; n < 4; n++) {
      int col = col0 + wc * 64 + n * 16 + lr;
      float bs = bias[col];
      #pragma unroll
      for (int m = 0; m < 4; m++) {
        #pragma unroll
        for (int r = 0; r < 4; r++) {
          int row = row0 + wr * 64 + m * 16 + lg * 4 + r;
          float v = acc[m][n][r] + bs;
          if (OMODE == 0) {
            ((u16*)Cptr)[(size_t)row * DM + col] = f2bf(v);
          } else {
            ((float*)Cptr)[(size_t)row * DM + col] = v;
          }
        }
      }
    }
  }
}

// XCD-local decode: id = 32a + 8b + c  ->  nt = b, mt = c + 8a.
static __device__ inline void xcd_decode(int id, int& nt, int& mt) {
  nt = (id >> 3) & 3;
  mt = (id & 7) + 8 * (id >> 5);
}

// fused Q-proj [0,1568) + K-proj [1568,1984) + V-proj [1984,2400)
__global__ __launch_bounds__(256) void qkvgemm_kernel(
    const u16* __restrict__ qbf, const u16* __restrict__ Wq,
    const float* __restrict__ bq, void* __restrict__ Qout,
    const u16* __restrict__ xln, const u16* __restrict__ Wk,
    const float* __restrict__ bk, void* __restrict__ Kout,
    const u16* __restrict__ Wv, const float* __restrict__ bv,
    void* __restrict__ Vout) {
  __shared__ __align__(16) u16 Al[2][128 * 32];
  __shared__ __align__(16) u16 Bl[2][128 * 32];
  int id = blockIdx.x;
  int nt, mt;
  if (id < 1568) {
    xcd_decode(id, nt, mt);
    gemm_body<0>(qbf, Wq, bq, Qout, nt, mt,
                 &Al[0][0], &Al[1][0], &Bl[0][0], &Bl[1][0]);
  } else if (id < 1984) {
    xcd_decode(id - 1568, nt, mt);
    gemm_body<0>(xln, Wk, bk, Kout, nt, mt,
                 &Al[0][0], &Al[1][0], &Bl[0][0], &Bl[1][0]);
  } else {
    xcd_decode(id - 1984, nt, mt);
    gemm_body<2>(xln, Wv, bv, Vout, nt, mt,
                 &Al[0][0], &Al[1][0], &Bl[0][0], &Bl[1][0]);
  }
}

// O-proj (fp32 out), XCD-local 1-D grid
__global__ __launch_bounds__(256) void ogemm_kernel(const u16* __restrict__ A,
                                                    const u16* __restrict__ Bw,
                                                    const float* __restrict__ bias,
                                                    void* __restrict__ Cptr) {
  __shared__ __align__(16) u16 Al[2][128 * 32];
  __shared__ __align__(16) u16 Bl[2][128 * 32];
  int nt, mt;
  xcd_decode(blockIdx.x, nt, mt);
  gemm_body<1>(A, Bw, bias, Cptr, nt, mt,
               &Al[0][0], &Al[1][0], &Bl[0][0], &Bl[1][0]);
}

// ---------------- fused attn: 8 waves, 1 head/wave, bf16 score exchange ----------------
// Round-22 change on the r19/r20 structure: raw scores stored in LDS as BF16
// (tiles are 512B, lane-order, 8B/lane b64 ops — conflict-free). s2 shrinks
// 2x16KB -> 2x8KB: attn LDS 48->32KB (5 blocks/CU by LDS; VGPR=64 allows 8
// waves/SIMD) and every mix-read halves b128->b64 (LDS pipe was the ~65%-busy
// bottleneck). Accuracy: raw-score bf16 rel-err 0.2% x mix weights ~0.044 ->
// mixed-score abs err ~1e-3 -> exp rel-err ~0.1%, below the existing bf16
// P-pack (0.4%). Unpack is shift/mask (1 VALU/float).
__global__ __launch_bounds__(512) void attn_kernel(const u16* __restrict__ Q,
                                                   const u16* __restrict__ K,
                                                   const u16* __restrict__ VTt,
                                                   const float* __restrict__ tw,
                                                   u16* __restrict__ Oat) {
  __shared__ __align__(16) u16 Kl[16 * 512];     // 16KB, chunk-major, single buf
  __shared__ __align__(16) u16 s2[2][16 * 256];  // 2 x 8KB, bf16 lane-order tiles
  int i = blockIdx.x;
  int g8 = i & 7;            // XCD group == b%8
  int j = i >> 3;            // 0..199
  int qc = j % 25;
  int b = g8 + 8 * (j / 25);
  int tid = threadIdx.x, wv = tid >> 6, lane = tid & 63;
  int lr = lane & 15, lg = lane >> 4;
  int q0A = qc * 32;
  int q0B = (qc < 24) ? (q0A + 16) : q0A;   // tail duplicates tile A
  // wave wv owns raw head wv AND output head wv

  const u16* Kb = K + (size_t)b * NKP * DM;
  const u16* Vtb = VTt + (size_t)b * 13 * 8192;

  float w0[8];
  #pragma unroll
  for (int h = 0; h < 8; h++)
    w0[h] = sgpr_f(tw[wv * 8 + h] * 0.125f);

  bf16x8 qr[2][2];   // [tile][half]
  #pragma unroll
  for (int t = 0; t < 2; t++) {
    const u16* Qb = Q + ((size_t)b * NQ + (t ? q0B : q0A)) * DM;
    qr[t][0] = ld8(Qb + (size_t)lr * DM + wv * 64 + lg * 8);
    qr[t][1] = ld8(Qb + (size_t)lr * DM + wv * 64 + 32 + lg * 8);
  }

  auto stageK = [&](int kt) {
    #pragma unroll
    for (int i2 = 0; i2 < 2; i2++) {
      int g = wv * 2 + i2;
      gl_lds16(Kb + (size_t)(kt * 16 + (lane & 15)) * DM + (g * 4 + (lane >> 4)) * 8,
               (char*)Kl + g * 1024);
    }
  };
  stageK(0);
  __syncthreads();

  f32x4 o[2][4] = {};      // [tile][j]
  float sumA = 0.f, sumB = 0.f;
  s16x4 vb[4];

  // mix + exp + PV for k-tile ktm, bf16 scores in s2[sbi]
  auto mixpv = [&](int ktm, int sbi) {
    bool masked = (ktm == 12) && (lg != 0);   // k >= 196
    s16x4 pa[2];
    #pragma unroll
    for (int t = 0; t < 2; t++) {
      f32x4 sa = {0.f, 0.f, 0.f, 0.f};
      #pragma unroll
      for (int h = 0; h < 8; h++) {
        uint2 sv = *reinterpret_cast<const uint2*>(
            &s2[sbi][0] + (t * 8 + h) * 256 + lane * 4);
        f32x4 scv = unpk4(sv);
        sa += scv * w0[h];
      }
      float e0 = masked ? 0.f : __expf(sa[0]);
      float e1 = masked ? 0.f : __expf(sa[1]);
      float e2 = masked ? 0.f : __expf(sa[2]);
      float e3 = masked ? 0.f : __expf(sa[3]);
      if (t == 0) sumA += (e0 + e1) + (e2 + e3);
      else        sumB += (e0 + e1) + (e2 + e3);
      union { __bf16 e[4]; s16x4 sv; } pk;
      pk.e[0] = (__bf16)e0; pk.e[1] = (__bf16)e1;
      pk.e[2] = (__bf16)e2; pk.e[3] = (__bf16)e3;
      pa[t] = pk.sv;
    }
    __builtin_amdgcn_s_setprio(1);
    #pragma unroll
    for (int t = 0; t < 2; t++) {
      #pragma unroll
      for (int j2 = 0; j2 < 4; j2++)
        o[t][j2] = mfma16k16(pa[t], vb[j2], o[t][j2]);
    }
    __builtin_amdgcn_s_setprio(0);
  };

  for (int kt = 0; kt < 13; kt++) {
    int bi = kt & 1;

    // EARLY V for the pipelined mix/PV of kt-1 (latency hidden under QK^T)
    if (kt > 0) {
      #pragma unroll
      for (int j2 = 0; j2 < 4; j2++) {
        int d = wv * 64 + j2 * 16 + lr;
        vb[j2] = *reinterpret_cast<const s16x4*>(
            Vtb + (size_t)(kt - 1) * 8192 + d * 16 + lg * 4);
      }
    }

    // QK^T(kt) for raw head wv, both tiles; write bf16 scores to s2[bi]
    const u16* kbase = Kl + lg * 128 + lr * 8;
    __builtin_amdgcn_s_setprio(1);
    {
      bf16x8 kf0 = ld8(kbase + wv * 1024);
      bf16x8 kf1 = ld8(kbase + wv * 1024 + 512);
      #pragma unroll
      for (int t = 0; t < 2; t++) {
        f32x4 tt = {0.f, 0.f, 0.f, 0.f};
        tt = mfma16(kf0, qr[t][0], tt);
        tt = mfma16(kf1, qr[t][1], tt);
        union { u16 s[4]; uint2 u; } pk;
        pk.s[0] = f2bf(tt[0]); pk.s[1] = f2bf(tt[1]);
        pk.s[2] = f2bf(tt[2]); pk.s[3] = f2bf(tt[3]);
        *reinterpret_cast<uint2*>(&s2[bi][0] + (t * 8 + wv) * 256 + lane * 4) = pk.u;
      }
    }
    __builtin_amdgcn_s_setprio(0);

    // fence: all kf ds_reads retired before this wave overwrites its eighth
    asm volatile("s_waitcnt lgkmcnt(0)" ::: "memory");
    __builtin_amdgcn_sched_barrier(0);
    if (kt < 12) stageK(kt + 1);

    // pipelined mix/exp/PV for kt-1 (scores from s2[bi^1])
    if (kt > 0) mixpv(kt - 1, bi ^ 1);

    __syncthreads();   // drains stage(kt+1) writes; s2[bi] visible for iter kt+1
  }
  // epilogue: mix/PV for kt=12
  {
    #pragma unroll
    for (int j2 = 0; j2 < 4; j2++) {
      int d = wv * 64 + j2 * 16 + lr;
      vb[j2] = *reinterpret_cast<const s16x4*>(
          Vtb + (size_t)12 * 8192 + d * 16 + lg * 4);
    }
    mixpv(12, 0);
  }

  sumA += __shfl_xor(sumA, 16); sumA += __shfl_xor(sumA, 32);
  sumB += __shfl_xor(sumB, 16); sumB += __shfl_xor(sumB, 32);
  float ivA = 1.0f / sumA, ivB = 1.0f / sumB;
  #pragma unroll
  for (int t = 0; t < 2; t++) {
    if (t == 1 && qc == 24) break;   // tail: tile B is a duplicate
    int q0 = t ? q0B : q0A;
    float ivsrc = t ? ivB : ivA;
    #pragma unroll
    for (int r = 0; r < 4; r++) {
      int q = lg * 4 + r;
      float iv = __shfl(ivsrc, q);   // sum lives at lane lr == q
      #pragma unroll
      for (int j2 = 0; j2 < 4; j2++) {
        Oat[((size_t)(b * NQ + q0 + q)) * DM + wv * 64 + j2 * 16 + lr] =
            f2bf(o[t][j2][r] * iv);
      }
    }
  }
}

// ---------------- launch ----------------
extern "C" void kernel_launch(void* const* d_in, const int* in_sizes, int n_in,
                              void* d_out, int out_size, void* d_ws, size_t ws_size,
                              hipStream_t stream) {
  const float* queries = (const float*)d_in[0];
  const float* Wq = (const float*)d_in[3];
  const float* bq = (const float*)d_in[4];
  const float* Wk = (const float*)d_in[5];
  const float* bk = (const float*)d_in[6];
  const float* Wv = (const float*)d_in[7];
  const float* bv = (const float*)d_in[8];
  const float* Wo = (const float*)d_in[9];
  const float* bo = (const float*)d_in[10];
  const float* sr_w = (const float*)d_in[11];
  const float* sr_b = (const float*)d_in[12];
  const float* ln_w = (const float*)d_in[13];
  const float* ln_b = (const float*)d_in[14];
  const float* tw = (const float*)d_in[15];

  char* ws = (char*)d_ws;
  u16* wq_bf = (u16*)(ws + 0);          // 512KB
  u16* wk_bf = (u16*)(ws + 524288);
  u16* wv_bf = (u16*)(ws + 1048576);
  u16* wo_bf = (u16*)(ws + 1572864);
  u16* xln   = (u16*)(ws + 2097152);    // 64*208*512*2 = 13,631,488
  u16* Kbuf  = (u16*)(ws + 15728640);   // 13,631,488
  u16* VTt   = (u16*)(ws + 29360128);   // 64*13*512*16*2 = 13,631,488
  u16* Qbuf  = (u16*)(ws + 42991616);   // 64*784*512*2 = 51,380,224
  u16* qbf   = (u16*)(ws + 94371840);   // 51,380,224 -> end 145,752,064
  u16* Oat   = qbf;                     // qbf dead after Q-proj; attn reuses it
  if (ws_size < 145752064u) return;     // fail loudly (output stays poisoned)

  // all 4 weight conversions in ONE launch (1024 blocks)
  cvt4_kernel<<<1024, 256, 0, stream>>>(Wq, Wk, Wv, Wo,
                                        wq_bf, wk_bf, wv_bf, wo_bf);

  // fused queries cvt + LN: 64*784 + 64*12 waves
  cvtln_kernel<<<(NB * NQ + NB * 12 + 3) / 4, 256, 0, stream>>>(
      queries, sr_w, sr_b, ln_w, ln_b, qbf, xln);

  // Q-proj + K-proj + V-proj in ONE launch, XCD-local A-panels
  qkvgemm_kernel<<<2400, 256, 0, stream>>>(qbf, wq_bf, bq, Qbuf,
                                           xln, wk_bf, bk, Kbuf,
                                           wv_bf, bv, VTt);

  attn_kernel<<<dim3(1600), 512, 0, stream>>>(Qbuf, Kbuf, VTt, tw, Oat);

  // out = Oat @ Wo^T + bo  (fp32 out), XCD-local A-panels
  ogemm_kernel<<<1568, 256, 0, stream>>>(Oat, wo_bf, bo, d_out);
}

// Round 23
// 230.000 us; speedup vs baseline: 1.1256x; 1.0472x over previous
//
#include <hip/hip_runtime.h>
#include <stdint.h>

typedef unsigned short u16;
typedef unsigned int   u32;
typedef __attribute__((ext_vector_type(8))) __bf16 bf16x8;
typedef __attribute__((ext_vector_type(4))) float  f32x4;
typedef __attribute__((ext_vector_type(4))) short  s16x4;

#define NB  64
#define NQ  784
#define NK  196
#define NKP 208      // nk padded to 13*16
#define DM  512

static __device__ inline u16 f2bf(float f) {
  u32 u = __float_as_uint(f);
  u32 r = (u + 0x7fffu + ((u >> 16) & 1u)) >> 16;
  return (u16)r;
}

static __device__ inline bf16x8 ld8(const u16* p) {
  return *reinterpret_cast<const bf16x8*>(p);
}
static __device__ inline f32x4 mfma16(bf16x8 a, bf16x8 b, f32x4 c) {
  return __builtin_amdgcn_mfma_f32_16x16x32_bf16(a, b, c, 0, 0, 0);
}
// K=16 bf16 MFMA (4 bf16 per lane per operand)
static __device__ inline f32x4 mfma16k16(s16x4 a, s16x4 b, f32x4 c) {
#if __has_builtin(__builtin_amdgcn_mfma_f32_16x16x16bf16_1k)
  return __builtin_amdgcn_mfma_f32_16x16x16bf16_1k(a, b, c, 0, 0, 0);
#elif __has_builtin(__builtin_amdgcn_mfma_f32_16x16x16_bf16)
  typedef __attribute__((ext_vector_type(4))) __bf16 bf16x4_t;
  union { s16x4 s; bf16x4_t b; } ua, ub;
  ua.s = a; ub.s = b;
  return __builtin_amdgcn_mfma_f32_16x16x16_bf16(ua.b, ub.b, c, 0, 0, 0);
#else
  asm volatile("v_mfma_f32_16x16x16_bf16 %0, %1, %2, %0\n\ts_nop 7\n\ts_nop 7"
               : "+v"(c) : "v"(a), "v"(b));
  return c;
#endif
}

// wave-uniform float -> SGPR
static __device__ inline float sgpr_f(float x) {
  return __uint_as_float(__builtin_amdgcn_readfirstlane(__float_as_uint(x)));
}

// async global -> LDS, 16B per lane; LDS dest must be wave-uniform base
static __device__ inline void gl_lds16(const void* g, void* l) {
  __builtin_amdgcn_global_load_lds(
      (const __attribute__((address_space(1))) void*)g,
      (__attribute__((address_space(3))) void*)l, 16, 0, 0);
}

// ---------------- fused queries cvt + LN + ALL weight conversions ---------------------
// wave ranges: [0, NB*NQ)           queries row cvt (+LN on subsample points)
//              [NB*NQ, +NB*12)      xln pad rows
//              [+, +4096)           weight cvt (4 x 1024 waves, 256 elems/wave)
__global__ __launch_bounds__(256) void cvtln_kernel(const float* __restrict__ q,
                                                    const float* __restrict__ sr_w,
                                                    const float* __restrict__ sr_b,
                                                    const float* __restrict__ ln_w,
                                                    const float* __restrict__ ln_b,
                                                    u16* __restrict__ qbf,
                                                    u16* __restrict__ xln,
                                                    const float* __restrict__ Wq,
                                                    const float* __restrict__ Wk,
                                                    const float* __restrict__ Wv,
                                                    const float* __restrict__ Wo,
                                                    u16* __restrict__ oq,
                                                    u16* __restrict__ ok,
                                                    u16* __restrict__ ov,
                                                    u16* __restrict__ oo) {
  int w = blockIdx.x * 4 + (threadIdx.x >> 6);
  int lane = threadIdx.x & 63;
  if (w >= NB * NQ) {
    int w2 = w - NB * NQ;
    if (w2 < NB * 12) {
      int b = w2 / 12, pr = w2 % 12;
      u16* outp = xln + ((size_t)(b * NKP + NK + pr)) * DM;
      *reinterpret_cast<uint4*>(outp + lane * 8) = make_uint4(0u, 0u, 0u, 0u);
      return;
    }
    int w3 = w2 - NB * 12;
    if (w3 < 4096) {
      int sel = w3 >> 10, widx = w3 & 1023;
      const float* in = (sel == 0) ? Wq : (sel == 1) ? Wk : (sel == 2) ? Wv : Wo;
      u16* out = (sel == 0) ? oq : (sel == 1) ? ok : (sel == 2) ? ov : oo;
      int i = widx * 256 + lane * 4;
      float4 f = *reinterpret_cast<const float4*>(in + i);
      ushort4 o;
      o.x = f2bf(f.x); o.y = f2bf(f.y); o.z = f2bf(f.z); o.w = f2bf(f.w);
      *reinterpret_cast<ushort4*>(out + i) = o;
    }
    return;
  }
  int b = w / NQ, n = w % NQ;
  const float* row = q + ((size_t)w) * DM;
  int c0 = lane * 4, c1 = 256 + lane * 4;
  float4 x0 = *reinterpret_cast<const float4*>(row + c0);
  float4 x1 = *reinterpret_cast<const float4*>(row + c1);
  u16* qp = qbf + (size_t)w * DM;
  ushort4 q0, q1;
  q0.x = f2bf(x0.x); q0.y = f2bf(x0.y); q0.z = f2bf(x0.z); q0.w = f2bf(x0.w);
  q1.x = f2bf(x1.x); q1.y = f2bf(x1.y); q1.z = f2bf(x1.z); q1.w = f2bf(x1.w);
  *reinterpret_cast<ushort4*>(qp + c0) = q0;
  *reinterpret_cast<ushort4*>(qp + c1) = q1;
  int y = n / 28, x = n % 28;
  if ((y & 1) | (x & 1)) return;
  int np = (y >> 1) * 14 + (x >> 1);
  float4 w0 = *reinterpret_cast<const float4*>(sr_w + c0);
  float4 w1 = *reinterpret_cast<const float4*>(sr_w + c1);
  float4 s0 = *reinterpret_cast<const float4*>(sr_b + c0);
  float4 s1 = *reinterpret_cast<const float4*>(sr_b + c1);
  float yv[8];
  yv[0] = x0.x * w0.x + s0.x; yv[1] = x0.y * w0.y + s0.y;
  yv[2] = x0.z * w0.z + s0.z; yv[3] = x0.w * w0.w + s0.w;
  yv[4] = x1.x * w1.x + s1.x; yv[5] = x1.y * w1.y + s1.y;
  yv[6] = x1.z * w1.z + s1.z; yv[7] = x1.w * w1.w + s1.w;
  float s = 0.f, ss = 0.f;
  #pragma unroll
  for (int i = 0; i < 8; i++) { s += yv[i]; ss += yv[i] * yv[i]; }
  #pragma unroll
  for (int off = 1; off < 64; off <<= 1) {
    s += __shfl_xor(s, off); ss += __shfl_xor(ss, off);
  }
  float mu = s * (1.f / 512.f);
  float var = ss * (1.f / 512.f) - mu * mu;
  float rs = rsqrtf(var + 1e-5f);
  float4 lw0 = *reinterpret_cast<const float4*>(ln_w + c0);
  float4 lw1 = *reinterpret_cast<const float4*>(ln_w + c1);
  float4 lb0 = *reinterpret_cast<const float4*>(ln_b + c0);
  float4 lb1 = *reinterpret_cast<const float4*>(ln_b + c1);
  ushort4 o0, o1;
  o0.x = f2bf((yv[0] - mu) * rs * lw0.x + lb0.x);
  o0.y = f2bf((yv[1] - mu) * rs * lw0.y + lb0.y);
  o0.z = f2bf((yv[2] - mu) * rs * lw0.z + lb0.z);
  o0.w = f2bf((yv[3] - mu) * rs * lw0.w + lb0.w);
  o1.x = f2bf((yv[4] - mu) * rs * lw1.x + lb1.x);
  o1.y = f2bf((yv[5] - mu) * rs * lw1.y + lb1.y);
  o1.z = f2bf((yv[6] - mu) * rs * lw1.z + lb1.z);
  o1.w = f2bf((yv[7] - mu) * rs * lw1.w + lb1.w);
  u16* outp = xln + ((size_t)(b * NKP + np)) * DM;
  *reinterpret_cast<ushort4*>(outp + c0) = o0;
  *reinterpret_cast<ushort4*>(outp + c1) = o1;
}

// ---------------- shared GEMM body: C[M,512] = A[M,512]*W[512,512]^T + bias ------------
template <int OMODE>
static __device__ __forceinline__ void gemm_body(const u16* __restrict__ A,
                                                 const u16* __restrict__ Bw,
                                                 const float* __restrict__ bias,
                                                 void* __restrict__ Cptr,
                                                 int nt, int mt,
                                                 u16* Al0, u16* Al1,
                                                 u16* Bl0, u16* Bl1) {
  int wv = threadIdx.x >> 6, lane = threadIdx.x & 63;
  int lr = lane & 15, lg = lane >> 4;
  int wr = wv >> 1, wc = wv & 1;
  int row0 = mt * 128, col0 = nt * 128;

  auto stage = [&](int kk, int bi) {
    u16* Al = bi ? Al1 : Al0;
    u16* Bl = bi ? Bl1 : Bl0;
    #pragma unroll
    for (int i = 0; i < 4; i++) {
      int t = wv * 4 + i;                    // 0..15
      int rr = (t & 7) * 16 + (lane >> 2);
      int cc = lane & 3;
      if (t < 8) {
        gl_lds16(A + (size_t)(row0 + rr) * DM + kk + cc * 8, (char*)Al + t * 1024);
      } else {
        gl_lds16(Bw + (size_t)(col0 + rr) * DM + kk + cc * 8, (char*)Bl + (t - 8) * 1024);
      }
    }
  };

  f32x4 acc[4][4] = {};
  stage(0, 0);
  __syncthreads();
  for (int s = 0; s < 16; s++) {
    int bi = s & 1;
    if (s < 15) stage((s + 1) * 32, bi ^ 1);
    u16* Al = bi ? Al1 : Al0;
    u16* Bl = bi ? Bl1 : Bl0;
    bf16x8 am[4], bn[4];
    #pragma unroll
    for (int m = 0; m < 4; m++)
      am[m] = ld8(Al + (wr * 64 + m * 16 + lr) * 32 + lg * 8);
    #pragma unroll
    for (int n = 0; n < 4; n++)
      bn[n] = ld8(Bl + (wc * 64 + n * 16 + lr) * 32 + lg * 8);
    #pragma unroll
    for (int m = 0; m < 4; m++)
      #pragma unroll
      for (int n = 0; n < 4; n++)
        acc[m][n] = mfma16(am[m], bn[n], acc[m][n]);
    __syncthreads();
  }
  if (OMODE == 2) {
    #pragma unroll
    for (int n = 0; n < 4; n++) {
      int col = col0 + wc * 64 + n * 16 + lr;
      float bs = bias[col];
      #pragma unroll
      for (int m = 0; m < 4; m++) {
        int rbase = row0 + wr * 64 + m * 16 + lg * 4;
        int bb = rbase / NKP;
        int kr = rbase % NKP;          // kr&15 == lg*4
        ushort4 o4;
        o4.x = f2bf(acc[m][n][0] + bs);
        o4.y = f2bf(acc[m][n][1] + bs);
        o4.z = f2bf(acc[m][n][2] + bs);
        o4.w = f2bf(acc[m][n][3] + bs);
        size_t dst = (((size_t)bb * 13 + (kr >> 4)) * 512 + col) * 16 + (kr & 15);
        *reinterpret_cast<ushort4*>(&((u16*)Cptr)[dst]) = o4;
      }
    }
  } else {
    #pragma unroll
    for (int n = 0; n < 4; n++) {
      int col = col0 + wc * 64 + n * 16 + lr;
      float bs = bias[col];
      #pragma unroll
      for (int m = 0; m < 4; m++) {
        #pragma unroll
        for (int r = 0; r < 4; r++) {
          int row = row0 + wr * 64 + m * 16 + lg * 4 + r;
          float v = acc[m][n][r] + bs;
          if (OMODE == 0) {
            ((u16*)Cptr)[(size_t)row * DM + col] = f2bf(v);
          } else {
            ((float*)Cptr)[(size_t)row * DM + col] = v;
          }
        }
      }
    }
  }
}

// XCD-local decode: id = 32a + 8b + c  ->  nt = b, mt = c + 8a.
static __device__ inline void xcd_decode(int id, int& nt, int& mt) {
  nt = (id >> 3) & 3;
  mt = (id & 7) + 8 * (id >> 5);
}

// fused Q-proj [0,1568) + K-proj [1568,1984) + V-proj [1984,2400)
__global__ __launch_bounds__(256) void qkvgemm_kernel(
    const u16* __restrict__ qbf, const u16* __restrict__ Wq,
    const float* __restrict__ bq, void* __restrict__ Qout,
    const u16* __restrict__ xln, const u16* __restrict__ Wk,
    const float* __restrict__ bk, void* __restrict__ Kout,
    const u16* __restrict__ Wv, const float* __restrict__ bv,
    void* __restrict__ Vout) {
  __shared__ __align__(16) u16 Al[2][128 * 32];
  __shared__ __align__(16) u16 Bl[2][128 * 32];
  int id = blockIdx.x;
  int nt, mt;
  if (id < 1568) {
    xcd_decode(id, nt, mt);
    gemm_body<0>(qbf, Wq, bq, Qout, nt, mt,
                 &Al[0][0], &Al[1][0], &Bl[0][0], &Bl[1][0]);
  } else if (id < 1984) {
    xcd_decode(id - 1568, nt, mt);
    gemm_body<0>(xln, Wk, bk, Kout, nt, mt,
                 &Al[0][0], &Al[1][0], &Bl[0][0], &Bl[1][0]);
  } else {
    xcd_decode(id - 1984, nt, mt);
    gemm_body<2>(xln, Wv, bv, Vout, nt, mt,
                 &Al[0][0], &Al[1][0], &Bl[0][0], &Bl[1][0]);
  }
}

// O-proj (fp32 out), XCD-local 1-D grid
__global__ __launch_bounds__(256) void ogemm_kernel(const u16* __restrict__ A,
                                                    const u16* __restrict__ Bw,
                                                    const float* __restrict__ bias,
                                                    void* __restrict__ Cptr) {
  __shared__ __align__(16) u16 Al[2][128 * 32];
  __shared__ __align__(16) u16 Bl[2][128 * 32];
  int nt, mt;
  xcd_decode(blockIdx.x, nt, mt);
  gemm_body<1>(A, Bw, bias, Cptr, nt, mt,
               &Al[0][0], &Al[1][0], &Bl[0][0], &Bl[1][0]);
}

// ---------------- fused attn: 512 threads, 8 waves, ONE head per wave ------------------
// (the proven round-19/20 version: fp32 score exchange, VGPR=64, ~98us)
__global__ __launch_bounds__(512) void attn_kernel(const u16* __restrict__ Q,
                                                   const u16* __restrict__ K,
                                                   const u16* __restrict__ VTt,
                                                   const float* __restrict__ tw,
                                                   u16* __restrict__ Oat) {
  __shared__ __align__(16) u16 Kl[16 * 512];      // 16KB, chunk-major, single buf
  __shared__ __align__(16) float s2[2][16 * 256]; // 2 x 16KB, lane-order tiles
  int i = blockIdx.x;
  int g8 = i & 7;            // XCD group == b%8
  int j = i >> 3;            // 0..199
  int qc = j % 25;
  int b = g8 + 8 * (j / 25);
  int tid = threadIdx.x, wv = tid >> 6, lane = tid & 63;
  int lr = lane & 15, lg = lane >> 4;
  int q0A = qc * 32;
  int q0B = (qc < 24) ? (q0A + 16) : q0A;   // tail duplicates tile A

  const u16* Kb = K + (size_t)b * NKP * DM;
  const u16* Vtb = VTt + (size_t)b * 13 * 8192;

  float w0[8];
  #pragma unroll
  for (int h = 0; h < 8; h++)
    w0[h] = sgpr_f(tw[wv * 8 + h] * 0.125f);

  bf16x8 qr[2][2];   // [tile][half]
  #pragma unroll
  for (int t = 0; t < 2; t++) {
    const u16* Qb = Q + ((size_t)b * NQ + (t ? q0B : q0A)) * DM;
    qr[t][0] = ld8(Qb + (size_t)lr * DM + wv * 64 + lg * 8);
    qr[t][1] = ld8(Qb + (size_t)lr * DM + wv * 64 + 32 + lg * 8);
  }

  auto stageK = [&](int kt) {
    #pragma unroll
    for (int i2 = 0; i2 < 2; i2++) {
      int g = wv * 2 + i2;
      gl_lds16(Kb + (size_t)(kt * 16 + (lane & 15)) * DM + (g * 4 + (lane >> 4)) * 8,
               (char*)Kl + g * 1024);
    }
  };
  stageK(0);
  __syncthreads();

  f32x4 o[2][4] = {};      // [tile][j]
  float sumA = 0.f, sumB = 0.f;
  s16x4 vb[4];

  auto mixpv = [&](int ktm, int sbi) {
    bool masked = (ktm == 12) && (lg != 0);   // k >= 196
    s16x4 pa[2];
    #pragma unroll
    for (int t = 0; t < 2; t++) {
      f32x4 sa = {0.f, 0.f, 0.f, 0.f};
      #pragma unroll
      for (int h = 0; h < 8; h++) {
        f32x4 scv = *reinterpret_cast<const f32x4*>(
            &s2[sbi][0] + (t * 8 + h) * 256 + lane * 4);
        sa += scv * w0[h];
      }
      float e0 = masked ? 0.f : __expf(sa[0]);
      float e1 = masked ? 0.f : __expf(sa[1]);
      float e2 = masked ? 0.f : __expf(sa[2]);
      float e3 = masked ? 0.f : __expf(sa[3]);
      if (t == 0) sumA += (e0 + e1) + (e2 + e3);
      else        sumB += (e0 + e1) + (e2 + e3);
      union { __bf16 e[4]; s16x4 sv; } pk;
      pk.e[0] = (__bf16)e0; pk.e[1] = (__bf16)e1;
      pk.e[2] = (__bf16)e2; pk.e[3] = (__bf16)e3;
      pa[t] = pk.sv;
    }
    __builtin_amdgcn_s_setprio(1);
    #pragma unroll
    for (int t = 0; t < 2; t++) {
      #pragma unroll
      for (int j2 = 0; j2 < 4; j2++)
        o[t][j2] = mfma16k16(pa[t], vb[j2], o[t][j2]);
    }
    __builtin_amdgcn_s_setprio(0);
  };

  for (int kt = 0; kt < 13; kt++) {
    int bi = kt & 1;

    if (kt > 0) {
      #pragma unroll
      for (int j2 = 0; j2 < 4; j2++) {
        int d = wv * 64 + j2 * 16 + lr;
        vb[j2] = *reinterpret_cast<const s16x4*>(
            Vtb + (size_t)(kt - 1) * 8192 + d * 16 + lg * 4);
      }
    }

    const u16* kbase = Kl + lg * 128 + lr * 8;
    __builtin_amdgcn_s_setprio(1);
    {
      bf16x8 kf0 = ld8(kbase + wv * 1024);
      bf16x8 kf1 = ld8(kbase + wv * 1024 + 512);
      #pragma unroll
      for (int t = 0; t < 2; t++) {
        f32x4 tt = {0.f, 0.f, 0.f, 0.f};
        tt = mfma16(kf0, qr[t][0], tt);
        tt = mfma16(kf1, qr[t][1], tt);
        *reinterpret_cast<f32x4*>(&s2[bi][0] + (t * 8 + wv) * 256 + lane * 4) = tt;
      }
    }
    __builtin_amdgcn_s_setprio(0);

    asm volatile("s_waitcnt lgkmcnt(0)" ::: "memory");
    __builtin_amdgcn_sched_barrier(0);
    if (kt < 12) stageK(kt + 1);

    if (kt > 0) mixpv(kt - 1, bi ^ 1);

    __syncthreads();
  }
  {
    #pragma unroll
    for (int j2 = 0; j2 < 4; j2++) {
      int d = wv * 64 + j2 * 16 + lr;
      vb[j2] = *reinterpret_cast<const s16x4*>(
          Vtb + (size_t)12 * 8192 + d * 16 + lg * 4);
    }
    mixpv(12, 0);
  }

  sumA += __shfl_xor(sumA, 16); sumA += __shfl_xor(sumA, 32);
  sumB += __shfl_xor(sumB, 16); sumB += __shfl_xor(sumB, 32);
  float ivA = 1.0f / sumA, ivB = 1.0f / sumB;
  #pragma unroll
  for (int t = 0; t < 2; t++) {
    if (t == 1 && qc == 24) break;   // tail: tile B is a duplicate
    int q0 = t ? q0B : q0A;
    float ivsrc = t ? ivB : ivA;
    #pragma unroll
    for (int r = 0; r < 4; r++) {
      int q = lg * 4 + r;
      float iv = __shfl(ivsrc, q);   // sum lives at lane lr == q
      #pragma unroll
      for (int j2 = 0; j2 < 4; j2++) {
        Oat[((size_t)(b * NQ + q0 + q)) * DM + wv * 64 + j2 * 16 + lr] =
            f2bf(o[t][j2][r] * iv);
      }
    }
  }
}

// ---------------- launch ----------------
extern "C" void kernel_launch(void* const* d_in, const int* in_sizes, int n_in,
                              void* d_out, int out_size, void* d_ws, size_t ws_size,
                              hipStream_t stream) {
  const float* queries = (const float*)d_in[0];
  const float* Wq = (const float*)d_in[3];
  const float* bq = (const float*)d_in[4];
  const float* Wk = (const float*)d_in[5];
  const float* bk = (const float*)d_in[6];
  const float* Wv = (const float*)d_in[7];
  const float* bv = (const float*)d_in[8];
  const float* Wo = (const float*)d_in[9];
  const float* bo = (const float*)d_in[10];
  const float* sr_w = (const float*)d_in[11];
  const float* sr_b = (const float*)d_in[12];
  const float* ln_w = (const float*)d_in[13];
  const float* ln_b = (const float*)d_in[14];
  const float* tw = (const float*)d_in[15];

  char* ws = (char*)d_ws;
  u16* wq_bf = (u16*)(ws + 0);          // 512KB
  u16* wk_bf = (u16*)(ws + 524288);
  u16* wv_bf = (u16*)(ws + 1048576);
  u16* wo_bf = (u16*)(ws + 1572864);
  u16* xln   = (u16*)(ws + 2097152);    // 64*208*512*2 = 13,631,488
  u16* Kbuf  = (u16*)(ws + 15728640);   // 13,631,488
  u16* VTt   = (u16*)(ws + 29360128);   // 64*13*512*16*2 = 13,631,488
  u16* Qbuf  = (u16*)(ws + 42991616);   // 64*784*512*2 = 51,380,224
  u16* qbf   = (u16*)(ws + 94371840);   // 51,380,224 -> end 145,752,064
  u16* Oat   = qbf;                     // qbf dead after Q-proj; attn reuses it
  if (ws_size < 145752064u) return;     // fail loudly (output stays poisoned)

  // queries cvt + LN + all 4 weight conversions in ONE launch
  // waves: 64*784 (rows) + 64*12 (pad) + 4096 (weights) = 55040 -> 13760 blocks
  cvtln_kernel<<<13760, 256, 0, stream>>>(queries, sr_w, sr_b, ln_w, ln_b,
                                          qbf, xln,
                                          Wq, Wk, Wv, Wo,
                                          wq_bf, wk_bf, wv_bf, wo_bf);

  // Q-proj + K-proj + V-proj in ONE launch, XCD-local A-panels
  qkvgemm_kernel<<<2400, 256, 0, stream>>>(qbf, wq_bf, bq, Qbuf,
                                           xln, wk_bf, bk, Kbuf,
                                           wv_bf, bv, VTt);

  attn_kernel<<<dim3(1600), 512, 0, stream>>>(Qbuf, Kbuf, VTt, tw, Oat);

  // out = Oat @ Wo^T + bo  (fp32 out), XCD-local A-panels
  ogemm_kernel<<<1568, 256, 0, stream>>>(Oat, wo_bf, bo, d_out);
}